// Round 3
// baseline (645.904 us; speedup 1.0000x reference)
//
#include <hip/hip_runtime.h>
#include <hip/hip_bf16.h>

// ScaledDotProductAttention: B=64, Lq=Lk=1024, D=64, temperature=8
// out = [output (64*1024*64 fp32) | attn (64*1024*1024 fp32)]

typedef __attribute__((ext_vector_type(8))) short bf16x8;
typedef __attribute__((ext_vector_type(4))) float f32x4;

static __device__ __forceinline__ bf16x8 pack8(float4 a, float4 b) {
    union { bf16x8 v; __hip_bfloat162 h[4]; } u;
    u.h[0] = __float22bfloat162_rn(make_float2(a.x, a.y));
    u.h[1] = __float22bfloat162_rn(make_float2(a.z, a.w));
    u.h[2] = __float22bfloat162_rn(make_float2(b.x, b.y));
    u.h[3] = __float22bfloat162_rn(make_float2(b.z, b.w));
    return u.v;
}
static __device__ __forceinline__ short f2bf(float f) {
    return (short)__builtin_bit_cast(unsigned short, __float2bfloat16(f));
}
static __device__ __forceinline__ float bf2f(short s) {
    unsigned u = ((unsigned)(unsigned short)s) << 16;
    return __builtin_bit_cast(float, u);
}

// ptile XOR swizzle: row r (0..15), col c (0..63) -> conflict-reduced, no pad
#define PIDX(r, c) ((r) * 64 + ((((c) >> 3) ^ ((r) & 7)) << 3) + ((c) & 7))

// ---------------------------------------------------------------------------
// pre-pass 1: mask int32 -> lane-native bit layout:
//   bits[row*16 + n] bit j = (mask[row][16*j + n] != 0)
__global__ __launch_bounds__(256) void pre_maskpack(const int* __restrict__ mask,
                                                    unsigned long long* __restrict__ bits) {
    const int L = threadIdx.x & 63;
    long wid = ((long)blockIdx.x * 256 + threadIdx.x) >> 6;  // global wave id
    const long nwaves = (long)gridDim.x * 4;
    for (long r = wid; r < 65536; r += nwaves) {
        const int4* p = (const int4*)(mask + r * 1024 + L * 16);
        int4 a = p[0], b = p[1], c = p[2], d = p[3];
        unsigned long long bl[16];
        bl[0]  = __ballot(a.x != 0); bl[1]  = __ballot(a.y != 0);
        bl[2]  = __ballot(a.z != 0); bl[3]  = __ballot(a.w != 0);
        bl[4]  = __ballot(b.x != 0); bl[5]  = __ballot(b.y != 0);
        bl[6]  = __ballot(b.z != 0); bl[7]  = __ballot(b.w != 0);
        bl[8]  = __ballot(c.x != 0); bl[9]  = __ballot(c.y != 0);
        bl[10] = __ballot(c.z != 0); bl[11] = __ballot(c.w != 0);
        bl[12] = __ballot(d.x != 0); bl[13] = __ballot(d.y != 0);
        bl[14] = __ballot(d.z != 0); bl[15] = __ballot(d.w != 0);
        unsigned long long x = bl[0];
        #pragma unroll
        for (int j = 1; j < 16; ++j) x = (L == j) ? bl[j] : x;
        if (L < 16) bits[r * 16 + L] = x;
    }
}

// pre-pass 2: straight fp32 -> bf16 convert (row-major == tiled layout for K)
__global__ __launch_bounds__(256) void pre_conv(const float* __restrict__ src,
                                                short* __restrict__ dst) {
    long i = (long)blockIdx.x * 256 + threadIdx.x;  // 524288 chunks of 8
    const float4* s = (const float4*)(src + i * 8);
    *(bf16x8*)(dst + i * 8) = pack8(s[0], s[1]);
}

// pre-pass 3: V fp32 -> bf16 transposed tiles [b*16+kt][d(64)][kpos(64)]
__global__ __launch_bounds__(256) void pre_vtrans(const float* __restrict__ v,
                                                  short* __restrict__ vt) {
    __shared__ short t[64][72];
    const int bkt = blockIdx.x;        // b*16 + kt
    const int tid = threadIdx.x;
    const int row = tid >> 2;          // kpos within tile
    const int cg  = (tid & 3) * 16;    // d start
    const float* src = v + ((long)bkt * 64 + row) * 64 + cg;
    float4 f0 = ((const float4*)src)[0];
    float4 f1 = ((const float4*)src)[1];
    float4 f2 = ((const float4*)src)[2];
    float4 f3 = ((const float4*)src)[3];
    float vv[16] = {f0.x, f0.y, f0.z, f0.w, f1.x, f1.y, f1.z, f1.w,
                    f2.x, f2.y, f2.z, f2.w, f3.x, f3.y, f3.z, f3.w};
    #pragma unroll
    for (int dd = 0; dd < 16; ++dd) t[cg + dd][row] = f2bf(vv[dd]);
    __syncthreads();
    const int d = tid >> 2, c0 = (tid & 3) * 16;
    short* dstrow = vt + (long)bkt * 4096 + d * 64;
    *(int4*)&dstrow[c0]     = *(int4*)&t[d][c0];
    *(int4*)&dstrow[c0 + 8] = *(int4*)&t[d][c0 + 8];
}

// ---------------------------------------------------------------------------
// main: ZERO barriers. Wave-private global bf16 fragment loads (L1/L2-hot),
// mask in 8 VGPRs, no-max softmax, 8KB LDS only for the C->A P round-trip.
__global__ __launch_bounds__(256, 4) void attn_main(
    const float* __restrict__ q, const unsigned long long* __restrict__ bits,
    const short* __restrict__ kb, const short* __restrict__ vt,
    float* __restrict__ out, float* __restrict__ attn)
{
    __shared__ short ptile[4][16 * 64];  // 8 KB total, XOR-swizzled

    const int tid  = threadIdx.x;
    const int w    = tid >> 6;
    const int L    = tid & 63;
    const int n    = L & 15;
    const int quad = L >> 4;
    const int b    = blockIdx.y;
    const long bq  = (long)b * 1024 + blockIdx.x * 64;

    const short* ktg = kb + (long)b * 65536;  // 16 tiles * 4096 shorts
    const short* vtg = vt + (long)b * 65536;

    // Q fragments (A-layout), scaled by 1/8, bf16
    const float* qrow = q + (bq + 16 * w + n) * 64 + quad * 8;
    float4 qa0 = ((const float4*)qrow)[0];
    float4 qa1 = ((const float4*)(qrow + 4))[0];
    float4 qb0 = ((const float4*)(qrow + 32))[0];
    float4 qb1 = ((const float4*)(qrow + 36))[0];
    const float sc = 0.125f;
    qa0.x *= sc; qa0.y *= sc; qa0.z *= sc; qa0.w *= sc;
    qa1.x *= sc; qa1.y *= sc; qa1.z *= sc; qa1.w *= sc;
    qb0.x *= sc; qb0.y *= sc; qb0.z *= sc; qb0.w *= sc;
    qb1.x *= sc; qb1.y *= sc; qb1.z *= sc; qb1.w *= sc;
    bf16x8 qf0 = pack8(qa0, qa1);
    bf16x8 qf1 = pack8(qb0, qb1);

    // per-lane mask bits: row 16w+quad*4+i, bit j of pk[i] = mask col 16j+n
    unsigned long long pk[4];
    #pragma unroll
    for (int i = 0; i < 4; ++i)
        pk[i] = bits[(bq + 16 * w + quad * 4 + i) * 16 + n];

    // ---------------- sweep 1: l per row (no max, no in-loop shuffles) ------
    float lp[4] = {0.f, 0.f, 0.f, 0.f};
    for (int kt = 0; kt < 16; ++kt) {
        const short* kt_base = ktg + kt * 4096;
        f32x4 acc[4];
        #pragma unroll
        for (int t = 0; t < 4; ++t) { acc[t][0]=0.f; acc[t][1]=0.f; acc[t][2]=0.f; acc[t][3]=0.f; }
        #pragma unroll
        for (int t = 0; t < 4; ++t) {
            const short* krow = kt_base + (t * 16 + n) * 64 + quad * 8;
            bf16x8 b0 = *(const bf16x8*)krow;
            bf16x8 b1 = *(const bf16x8*)(krow + 32);
            acc[t] = __builtin_amdgcn_mfma_f32_16x16x32_bf16(qf0, b0, acc[t], 0, 0, 0);
            acc[t] = __builtin_amdgcn_mfma_f32_16x16x32_bf16(qf1, b1, acc[t], 0, 0, 0);
        }
        #pragma unroll
        for (int i = 0; i < 4; ++i) {
            unsigned nib = (unsigned)(pk[i] >> (4 * kt)) & 15u;
            float e0 = (nib & 1u) ? 0.f : __expf(acc[0][i]);
            float e1 = (nib & 2u) ? 0.f : __expf(acc[1][i]);
            float e2 = (nib & 4u) ? 0.f : __expf(acc[2][i]);
            float e3 = (nib & 8u) ? 0.f : __expf(acc[3][i]);
            lp[i] += (e0 + e1) + (e2 + e3);
        }
    }
    float linv[4];
    #pragma unroll
    for (int i = 0; i < 4; ++i) {
        float l = lp[i];
        l += __shfl_xor(l, 1);
        l += __shfl_xor(l, 2);
        l += __shfl_xor(l, 4);
        l += __shfl_xor(l, 8);
        linv[i] = 1.0f / l;
    }

    // ---------------- sweep 2: recompute S -> P, write attn, P@V ------------
    f32x4 oacc[4];
    #pragma unroll
    for (int t = 0; t < 4; ++t) { oacc[t][0]=0.f; oacc[t][1]=0.f; oacc[t][2]=0.f; oacc[t][3]=0.f; }

    float* attn_row = attn + (bq + 16 * w + n) * 1024;
    short* pw = ptile[w];

    for (int kt = 0; kt < 16; ++kt) {
        const short* kt_base = ktg + kt * 4096;
        f32x4 acc[4];
        #pragma unroll
        for (int t = 0; t < 4; ++t) { acc[t][0]=0.f; acc[t][1]=0.f; acc[t][2]=0.f; acc[t][3]=0.f; }
        #pragma unroll
        for (int t = 0; t < 4; ++t) {
            const short* krow = kt_base + (t * 16 + n) * 64 + quad * 8;
            bf16x8 b0 = *(const bf16x8*)krow;
            bf16x8 b1 = *(const bf16x8*)(krow + 32);
            acc[t] = __builtin_amdgcn_mfma_f32_16x16x32_bf16(qf0, b0, acc[t], 0, 0, 0);
            acc[t] = __builtin_amdgcn_mfma_f32_16x16x32_bf16(qf1, b1, acc[t], 0, 0, 0);
        }
        // P (normalized) -> per-wave LDS tile (C-layout in, A-layout out)
        #pragma unroll
        for (int i = 0; i < 4; ++i) {
            unsigned nib = (unsigned)(pk[i] >> (4 * kt)) & 15u;
            float p0 = (nib & 1u) ? 0.f : __expf(acc[0][i]) * linv[i];
            float p1 = (nib & 2u) ? 0.f : __expf(acc[1][i]) * linv[i];
            float p2 = (nib & 4u) ? 0.f : __expf(acc[2][i]) * linv[i];
            float p3 = (nib & 8u) ? 0.f : __expf(acc[3][i]) * linv[i];
            int r = quad * 4 + i;
            pw[PIDX(r, n)]      = f2bf(p0);
            pw[PIDX(r, 16 + n)] = f2bf(p1);
            pw[PIDX(r, 32 + n)] = f2bf(p2);
            pw[PIDX(r, 48 + n)] = f2bf(p3);
        }
        // same-wave in-order DS pipe: reads see the writes above
        bf16x8 pf0 = *(const bf16x8*)&pw[n * 64 + ((quad ^ (n & 7)) << 3)];
        bf16x8 pf1 = *(const bf16x8*)&pw[n * 64 + (((4 + quad) ^ (n & 7)) << 3)];
        // attn write (bf16 -> fp32 widen, coalesced 16B stores)
        float* ap = attn_row + kt * 64;
        float4 f0, f1, g0, g1;
        f0.x = bf2f(pf0[0]); f0.y = bf2f(pf0[1]); f0.z = bf2f(pf0[2]); f0.w = bf2f(pf0[3]);
        f1.x = bf2f(pf0[4]); f1.y = bf2f(pf0[5]); f1.z = bf2f(pf0[6]); f1.w = bf2f(pf0[7]);
        g0.x = bf2f(pf1[0]); g0.y = bf2f(pf1[1]); g0.z = bf2f(pf1[2]); g0.w = bf2f(pf1[3]);
        g1.x = bf2f(pf1[4]); g1.y = bf2f(pf1[5]); g1.z = bf2f(pf1[6]); g1.w = bf2f(pf1[7]);
        *(float4*)(ap + quad * 8)          = f0;
        *(float4*)(ap + quad * 8 + 4)      = f1;
        *(float4*)(ap + 32 + quad * 8)     = g0;
        *(float4*)(ap + 32 + quad * 8 + 4) = g1;
        // P @ V from global V^T tiles
        const short* vt_base = vtg + kt * 4096;
        #pragma unroll
        for (int t = 0; t < 4; ++t) {
            const short* vrow = vt_base + (t * 16 + n) * 64 + quad * 8;
            bf16x8 v0 = *(const bf16x8*)vrow;
            bf16x8 v1 = *(const bf16x8*)(vrow + 32);
            oacc[t] = __builtin_amdgcn_mfma_f32_16x16x32_bf16(pf0, v0, oacc[t], 0, 0, 0);
            oacc[t] = __builtin_amdgcn_mfma_f32_16x16x32_bf16(pf1, v1, oacc[t], 0, 0, 0);
        }
    }

    #pragma unroll
    for (int t = 0; t < 4; ++t)
        #pragma unroll
        for (int i = 0; i < 4; ++i)
            out[(bq + 16 * w + quad * 4 + i) * 64 + t * 16 + n] = oacc[t][i];
}

// ---------------------------------------------------------------------------
// fallback (round-1 kernel) for small ws_size
#define KSTRIDE 72
#define PSTRIDE 68
__global__ __launch_bounds__(256) void attn_fallback(
    const float* __restrict__ q, const float* __restrict__ k,
    const float* __restrict__ v, const int* __restrict__ mask,
    float* __restrict__ out, float* __restrict__ attn)
{
    __shared__ unsigned maskbits[64][32];
    __shared__ short kbuf[64 * KSTRIDE];
    __shared__ short vtbuf[64 * KSTRIDE];
    __shared__ float ptilef[4 * 16 * PSTRIDE];

    const int tid  = threadIdx.x;
    const int w    = tid >> 6;
    const int L    = tid & 63;
    const int n    = L & 15;
    const int quad = L >> 4;
    const int b    = blockIdx.y;
    const long bq  = (long)b * 1024 + blockIdx.x * 64;

    const float* qrow = q + (bq + 16 * w + n) * 64 + quad * 8;
    float4 qa0 = ((const float4*)qrow)[0];
    float4 qa1 = ((const float4*)(qrow + 4))[0];
    float4 qb0 = ((const float4*)(qrow + 32))[0];
    float4 qb1 = ((const float4*)(qrow + 36))[0];
    const float sc = 0.125f;
    qa0.x *= sc; qa0.y *= sc; qa0.z *= sc; qa0.w *= sc;
    qa1.x *= sc; qa1.y *= sc; qa1.z *= sc; qa1.w *= sc;
    qb0.x *= sc; qb0.y *= sc; qb0.z *= sc; qb0.w *= sc;
    qb1.x *= sc; qb1.y *= sc; qb1.z *= sc; qb1.w *= sc;
    bf16x8 qf0 = pack8(qa0, qa1);
    bf16x8 qf1 = pack8(qb0, qb1);

    #pragma unroll
    for (int ii = 0; ii < 8; ++ii) {
        int wi  = ii * 256 + tid;
        int row = wi >> 5;
        int wc  = wi & 31;
        const int4* mp = (const int4*)(mask + (bq + row) * 1024 + wc * 32);
        unsigned word = 0;
        #pragma unroll
        for (int j = 0; j < 8; ++j) {
            int4 m4 = mp[j];
            word |= (m4.x != 0 ? 1u : 0u) << (4 * j + 0);
            word |= (m4.y != 0 ? 1u : 0u) << (4 * j + 1);
            word |= (m4.z != 0 ? 1u : 0u) << (4 * j + 2);
            word |= (m4.w != 0 ? 1u : 0u) << (4 * j + 3);
        }
        maskbits[row][wc] = word;
    }

    float m_i[4] = {-1e30f, -1e30f, -1e30f, -1e30f};
    float l_i[4] = {0.f, 0.f, 0.f, 0.f};

    for (int kt = 0; kt < 16; ++kt) {
        __syncthreads();
        {
            const float* kr = k + ((long)b * 1024 + kt * 64 + L) * 64 + w * 16;
            float4 k0 = ((const float4*)kr)[0];
            float4 k1 = ((const float4*)kr)[1];
            float4 k2 = ((const float4*)kr)[2];
            float4 k3 = ((const float4*)kr)[3];
            bf16x8* dst = (bf16x8*)&kbuf[L * KSTRIDE + w * 16];
            dst[0] = pack8(k0, k1);
            dst[1] = pack8(k2, k3);
        }
        __syncthreads();
        f32x4 acc[4];
        #pragma unroll
        for (int t = 0; t < 4; ++t) { acc[t][0]=0.f; acc[t][1]=0.f; acc[t][2]=0.f; acc[t][3]=0.f; }
        #pragma unroll
        for (int t = 0; t < 4; ++t) {
            bf16x8 b0 = *(const bf16x8*)&kbuf[(t * 16 + n) * KSTRIDE + quad * 8];
            bf16x8 b1 = *(const bf16x8*)&kbuf[(t * 16 + n) * KSTRIDE + 32 + quad * 8];
            acc[t] = __builtin_amdgcn_mfma_f32_16x16x32_bf16(qf0, b0, acc[t], 0, 0, 0);
            acc[t] = __builtin_amdgcn_mfma_f32_16x16x32_bf16(qf1, b1, acc[t], 0, 0, 0);
        }
        #pragma unroll
        for (int i = 0; i < 4; ++i) {
            int mrow = 16 * w + quad * 4 + i;
            unsigned w0 = maskbits[mrow][kt * 2];
            unsigned w1 = maskbits[mrow][kt * 2 + 1];
            float s0 = ((w0 >> n)        & 1u) ? -1e30f : acc[0][i];
            float s1 = ((w0 >> (16 + n)) & 1u) ? -1e30f : acc[1][i];
            float s2 = ((w1 >> n)        & 1u) ? -1e30f : acc[2][i];
            float s3 = ((w1 >> (16 + n)) & 1u) ? -1e30f : acc[3][i];
            float mt = fmaxf(fmaxf(s0, s1), fmaxf(s2, s3));
            mt = fmaxf(mt, __shfl_xor(mt, 1));
            mt = fmaxf(mt, __shfl_xor(mt, 2));
            mt = fmaxf(mt, __shfl_xor(mt, 4));
            mt = fmaxf(mt, __shfl_xor(mt, 8));
            float mnew = fmaxf(m_i[i], mt);
            float ps = __expf(s0 - mnew) + __expf(s1 - mnew)
                     + __expf(s2 - mnew) + __expf(s3 - mnew);
            ps += __shfl_xor(ps, 1);
            ps += __shfl_xor(ps, 2);
            ps += __shfl_xor(ps, 4);
            ps += __shfl_xor(ps, 8);
            l_i[i] = l_i[i] * __expf(m_i[i] - mnew) + ps;
            m_i[i] = mnew;
        }
    }
    float linv[4];
    #pragma unroll
    for (int i = 0; i < 4; ++i) linv[i] = 1.0f / l_i[i];

    f32x4 oacc[4];
    #pragma unroll
    for (int t = 0; t < 4; ++t) { oacc[t][0]=0.f; oacc[t][1]=0.f; oacc[t][2]=0.f; oacc[t][3]=0.f; }
    float* attn_row = attn + (bq + 16 * w + n) * 1024;

    for (int kt = 0; kt < 16; ++kt) {
        __syncthreads();
        {
            const float* kr = k + ((long)b * 1024 + kt * 64 + L) * 64 + w * 16;
            float4 k0 = ((const float4*)kr)[0];
            float4 k1 = ((const float4*)kr)[1];
            float4 k2 = ((const float4*)kr)[2];
            float4 k3 = ((const float4*)kr)[3];
            bf16x8* dst = (bf16x8*)&kbuf[L * KSTRIDE + w * 16];
            dst[0] = pack8(k0, k1);
            dst[1] = pack8(k2, k3);
            const float* vr = v + ((long)b * 1024 + kt * 64 + L) * 64 + w * 16;
            float4 v0 = ((const float4*)vr)[0];
            float4 v1 = ((const float4*)vr)[1];
            float4 v2 = ((const float4*)vr)[2];
            float4 v3 = ((const float4*)vr)[3];
            float vv[16] = {v0.x, v0.y, v0.z, v0.w, v1.x, v1.y, v1.z, v1.w,
                            v2.x, v2.y, v2.z, v2.w, v3.x, v3.y, v3.z, v3.w};
            #pragma unroll
            for (int dd = 0; dd < 16; ++dd)
                vtbuf[(w * 16 + dd) * KSTRIDE + L] = f2bf(vv[dd]);
        }
        __syncthreads();
        f32x4 acc[4];
        #pragma unroll
        for (int t = 0; t < 4; ++t) { acc[t][0]=0.f; acc[t][1]=0.f; acc[t][2]=0.f; acc[t][3]=0.f; }
        #pragma unroll
        for (int t = 0; t < 4; ++t) {
            bf16x8 b0 = *(const bf16x8*)&kbuf[(t * 16 + n) * KSTRIDE + quad * 8];
            bf16x8 b1 = *(const bf16x8*)&kbuf[(t * 16 + n) * KSTRIDE + 32 + quad * 8];
            acc[t] = __builtin_amdgcn_mfma_f32_16x16x32_bf16(qf0, b0, acc[t], 0, 0, 0);
            acc[t] = __builtin_amdgcn_mfma_f32_16x16x32_bf16(qf1, b1, acc[t], 0, 0, 0);
        }
        #pragma unroll
        for (int i = 0; i < 4; ++i) {
            int mrow = 16 * w + quad * 4 + i;
            unsigned w0 = maskbits[mrow][kt * 2];
            unsigned w1 = maskbits[mrow][kt * 2 + 1];
            float s0 = ((w0 >> n)        & 1u) ? -1e30f : acc[0][i];
            float s1 = ((w0 >> (16 + n)) & 1u) ? -1e30f : acc[1][i];
            float s2 = ((w1 >> n)        & 1u) ? -1e30f : acc[2][i];
            float s3 = ((w1 >> (16 + n)) & 1u) ? -1e30f : acc[3][i];
            float* pr = &ptilef[(w * 16 + quad * 4 + i) * PSTRIDE];
            pr[n]      = __expf(s0 - m_i[i]) * linv[i];
            pr[16 + n] = __expf(s1 - m_i[i]) * linv[i];
            pr[32 + n] = __expf(s2 - m_i[i]) * linv[i];
            pr[48 + n] = __expf(s3 - m_i[i]) * linv[i];
        }
        bf16x8 pf[2];
        #pragma unroll
        for (int c = 0; c < 2; ++c) {
            const float* pp = &ptilef[(w * 16 + n) * PSTRIDE + c * 32 + quad * 8];
            float4 p0 = ((const float4*)pp)[0];
            float4 p1 = ((const float4*)pp)[1];
            float* ap = attn_row + kt * 64 + c * 32 + quad * 8;
            ((float4*)ap)[0] = p0;
            ((float4*)ap)[1] = p1;
            pf[c] = pack8(p0, p1);
        }
        #pragma unroll
        for (int t = 0; t < 4; ++t) {
            bf16x8 vb0 = *(const bf16x8*)&vtbuf[(t * 16 + n) * KSTRIDE + quad * 8];
            bf16x8 vb1 = *(const bf16x8*)&vtbuf[(t * 16 + n) * KSTRIDE + 32 + quad * 8];
            oacc[t] = __builtin_amdgcn_mfma_f32_16x16x32_bf16(pf[0], vb0, oacc[t], 0, 0, 0);
            oacc[t] = __builtin_amdgcn_mfma_f32_16x16x32_bf16(pf[1], vb1, oacc[t], 0, 0, 0);
        }
    }
    #pragma unroll
    for (int t = 0; t < 4; ++t)
        #pragma unroll
        for (int i = 0; i < 4; ++i)
            out[(bq + 16 * w + quad * 4 + i) * 64 + t * 16 + n] = oacc[t][i];
}

extern "C" void kernel_launch(void* const* d_in, const int* in_sizes, int n_in,
                              void* d_out, int out_size, void* d_ws, size_t ws_size,
                              hipStream_t stream) {
    const float* q    = (const float*)d_in[0];
    const float* k    = (const float*)d_in[1];
    const float* v    = (const float*)d_in[2];
    const int*   mask = (const int*)d_in[3];
    float* out  = (float*)d_out;
    float* attn = out + (long)64 * 1024 * 64;

    dim3 grid(16, 64, 1);
    dim3 block(256, 1, 1);

    const size_t need = (size_t)24 << 20;  // 8MB bits + 8MB K bf16 + 8MB V^T bf16
    if (ws_size >= need) {
        unsigned char* ws = (unsigned char*)d_ws;
        unsigned long long* bits = (unsigned long long*)ws;
        short* kbw = (short*)(ws + ((size_t)8 << 20));
        short* vtw = (short*)(ws + ((size_t)16 << 20));
        pre_maskpack<<<2048, 256, 0, stream>>>(mask, bits);
        pre_conv<<<2048, 256, 0, stream>>>(k, kbw);
        pre_vtrans<<<1024, 256, 0, stream>>>(v, vtw);
        attn_main<<<grid, block, 0, stream>>>(q, bits, kbw, vtw, out, attn);
    } else {
        attn_fallback<<<grid, block, 0, stream>>>(q, k, v, mask, out, attn);
    }
}

// Round 4
// 542.375 us; speedup vs baseline: 1.1909x; 1.1909x over previous
//
#include <hip/hip_runtime.h>
#include <hip/hip_bf16.h>

// ScaledDotProductAttention: B=64, Lq=Lk=1024, D=64, temperature=8
// out = [output (64*1024*64 fp32) | attn (64*1024*1024 fp32)]

typedef __attribute__((ext_vector_type(8))) short bf16x8;
typedef __attribute__((ext_vector_type(4))) short bf16x4;
typedef __attribute__((ext_vector_type(4))) float f32x4;

#define GLOBAL_AS __attribute__((address_space(1)))
#define LDS_AS    __attribute__((address_space(3)))

static __device__ __forceinline__ short f2bf(float f) {
    return (short)__builtin_bit_cast(unsigned short, __float2bfloat16(f));
}
static __device__ __forceinline__ bf16x8 pack8(float4 a, float4 b) {
    union { bf16x8 v; __hip_bfloat162 h[4]; } u;
    u.h[0] = __float22bfloat162_rn(make_float2(a.x, a.y));
    u.h[1] = __float22bfloat162_rn(make_float2(a.z, a.w));
    u.h[2] = __float22bfloat162_rn(make_float2(b.x, b.y));
    u.h[3] = __float22bfloat162_rn(make_float2(b.z, b.w));
    return u.v;
}
static __device__ __forceinline__ bf16x4 pack4(float a, float b, float c, float d) {
    union { bf16x4 v; __hip_bfloat162 h[2]; } u;
    u.h[0] = __float22bfloat162_rn(make_float2(a, b));
    u.h[1] = __float22bfloat162_rn(make_float2(c, d));
    return u.v;
}

// wave-wide 1KB async global->LDS copy: lds dest = uniform base + lane*16
static __device__ __forceinline__ void dma16(void* lds, const void* g) {
    __builtin_amdgcn_global_load_lds((const GLOBAL_AS unsigned*)g,
                                     (LDS_AS unsigned*)lds, 16, 0, 0);
}
// stage an 8KB tile (64 rows x 128B): 2 insts per wave
static __device__ __forceinline__ void stage8k(short* lds, const short* g, int w, int L) {
    dma16((void*)(lds + (w * 2 + 0) * 512), (const void*)(g + (w * 2 + 0) * 512 + L * 8));
    dma16((void*)(lds + (w * 2 + 1) * 512), (const void*)(g + (w * 2 + 1) * 512 + L * 8));
}

// ---------------------------------------------------------------------------
// pre-pass 1: mask int32 -> per-(row,ktile) 64-bit word; bit j = mask[row][kt*64+j]
__global__ __launch_bounds__(256) void pre_maskpack(const int* __restrict__ mask,
                                                    unsigned long long* __restrict__ bits) {
    const int L = threadIdx.x & 63;
    long r = ((long)blockIdx.x * 256 + threadIdx.x) >> 6;  // row 0..65535
    const int* row = mask + r * 1024;
    unsigned long long bl[16];
    #pragma unroll
    for (int kt = 0; kt < 16; ++kt)
        bl[kt] = __ballot(row[kt * 64 + L] != 0);
    unsigned long long x = bl[0];
    #pragma unroll
    for (int j = 1; j < 16; ++j) x = (L == j) ? bl[j] : x;
    if (L < 16) bits[r * 16 + L] = x;
}

// pre-pass 2 (fused): K fp32 -> bf16 swizzled tiles  |  V fp32 -> bf16 V^T swizzled tiles
// tile layout: [b*16+kt][row(64)][8 chunks of 8 shorts, chunk c stored at c^(row&7)]
__global__ __launch_bounds__(256) void pre_kv(const float* __restrict__ k,
                                              const float* __restrict__ v,
                                              short* __restrict__ kb,
                                              short* __restrict__ vt) {
    __shared__ short t[64][72];
    const int tid = threadIdx.x;
    if (blockIdx.x < 2048) {
        long ci = (long)blockIdx.x * 256 + tid;   // 524288 chunks of 8 floats
        long row = ci >> 3;                       // b*1024 + kpos
        int  c   = (int)(ci & 7);
        const float4* s = (const float4*)(k + row * 64 + c * 8);
        int r = (int)(row & 63);
        short* dst = kb + (row >> 6) * 4096 + (long)r * 64 + ((c ^ (r & 7)) << 3);
        *(bf16x8*)dst = pack8(s[0], s[1]);
    } else {
        const int bkt = blockIdx.x - 2048;        // b*16 + kt
        const int row = tid >> 2;                 // kpos within tile
        const int cg  = (tid & 3) * 16;           // d start
        const float* src = v + ((long)bkt * 64 + row) * 64 + cg;
        float4 f0 = ((const float4*)src)[0];
        float4 f1 = ((const float4*)src)[1];
        float4 f2 = ((const float4*)src)[2];
        float4 f3 = ((const float4*)src)[3];
        float vv[16] = {f0.x, f0.y, f0.z, f0.w, f1.x, f1.y, f1.z, f1.w,
                        f2.x, f2.y, f2.z, f2.w, f3.x, f3.y, f3.z, f3.w};
        #pragma unroll
        for (int dd = 0; dd < 16; ++dd) t[cg + dd][row] = f2bf(vv[dd]);
        __syncthreads();
        const int d = tid >> 2, c0 = (tid & 3) * 2;
        short* dstrow = vt + (long)bkt * 4096 + d * 64;
        *(int4*)&dstrow[((c0 ^ (d & 7)) << 3)]       = *(int4*)&t[d][c0 * 8];
        *(int4*)&dstrow[(((c0 + 1) ^ (d & 7)) << 3)] = *(int4*)&t[d][c0 * 8 + 8];
    }
}

// ---------------------------------------------------------------------------
// main: S^T scheme. QK^T computed transposed (swap MFMA operands) so qrow = lane&15
// for every register: scalar linv/lane, 64-bit mask word per (row,kt), fp32 attn
// stores straight from regs, cheap P^T->A-layout LDS round-trip (b64 w / b128 r).
__global__ __launch_bounds__(256, 4) void attn_main(
    const float* __restrict__ q, const unsigned long long* __restrict__ bits,
    const short* __restrict__ kb, const short* __restrict__ vt,
    float* __restrict__ out, float* __restrict__ attn)
{
    __shared__ short kbuf[2][4096];     // 16 KB
    __shared__ short vbuf[2][4096];     // 16 KB
    __shared__ short ptile[4][1024];    // 8 KB (per-wave P round-trip, swizzled)

    const int tid  = threadIdx.x;
    const int w    = tid >> 6;
    const int L    = tid & 63;
    const int n    = L & 15;    // qrow within wave-tile (for ALL regs)
    const int g    = L >> 4;
    const int b    = blockIdx.y;
    const long bq  = (long)b * 1024 + blockIdx.x * 64;

    const short* ktg = kb + (long)b * 65536;
    const short* vtg = vt + (long)b * 65536;

    // Q fragments, scale = 1/8 * log2(e)  (exp(s) == exp2(s*log2e), exact identity)
    const float* qrow = q + (bq + 16 * w + n) * 64 + g * 8;
    float4 qa0 = ((const float4*)qrow)[0];
    float4 qa1 = ((const float4*)(qrow + 4))[0];
    float4 qb0 = ((const float4*)(qrow + 32))[0];
    float4 qb1 = ((const float4*)(qrow + 36))[0];
    const float sc = 0.125f * 1.4426950408889634f;
    qa0.x *= sc; qa0.y *= sc; qa0.z *= sc; qa0.w *= sc;
    qa1.x *= sc; qa1.y *= sc; qa1.z *= sc; qa1.w *= sc;
    qb0.x *= sc; qb0.y *= sc; qb0.z *= sc; qb0.w *= sc;
    qb1.x *= sc; qb1.y *= sc; qb1.z *= sc; qb1.w *= sc;
    bf16x8 qf0 = pack8(qa0, qa1);
    bf16x8 qf1 = pack8(qb0, qb1);

    const unsigned long long* mrow_ptr = bits + (bq + 16 * w + n) * 16;
    const int sw = (n & 7);  // row swizzle key for all 64-short LDS rows

    // ---------------- sweep 1: l per q-row ----------------------------------
    float lp = 0.f;
    stage8k(kbuf[0], ktg, w, L);
    __syncthreads();

    for (int kt = 0; kt < 16; ++kt) {
        if (kt < 15) {
            stage8k(kbuf[(kt + 1) & 1], ktg + (kt + 1) * 4096, w, L);
        } else {  // prefetch sweep-2 tile 0
            stage8k(kbuf[0], ktg, w, L);
            stage8k(vbuf[0], vtg, w, L);
        }
        unsigned long long mrow = mrow_ptr[kt];
        const short* kl = kbuf[kt & 1];
        f32x4 acc[4];
        #pragma unroll
        for (int t = 0; t < 4; ++t) { acc[t][0]=0.f; acc[t][1]=0.f; acc[t][2]=0.f; acc[t][3]=0.f; }
        #pragma unroll
        for (int t = 0; t < 4; ++t) {
            // S^T tile: A = K rows (lane&15 = kpos), B = Q^T (lane&15 = qrow)
            bf16x8 kf0 = *(const bf16x8*)&kl[(t * 16 + n) * 64 + ((g ^ sw) << 3)];
            bf16x8 kf1 = *(const bf16x8*)&kl[(t * 16 + n) * 64 + (((4 + g) ^ sw) << 3)];
            acc[t] = __builtin_amdgcn_mfma_f32_16x16x32_bf16(kf0, qf0, acc[t], 0, 0, 0);
            acc[t] = __builtin_amdgcn_mfma_f32_16x16x32_bf16(kf1, qf1, acc[t], 0, 0, 0);
        }
        unsigned long long ms = mrow >> (g * 4);
        #pragma unroll
        for (int t = 0; t < 4; ++t)
            #pragma unroll
            for (int i = 0; i < 4; ++i) {
                unsigned bit = (unsigned)(ms >> (t * 16 + i)) & 1u;
                lp += bit ? 0.f : __builtin_exp2f(acc[t][i]);
            }
        __syncthreads();
    }
    float l = lp + __shfl_xor(lp, 16);
    l += __shfl_xor(l, 32);
    const float linv = 1.0f / l;

    // ---------------- sweep 2: P^T, attn stores, P@V ------------------------
    f32x4 oacc[4];
    #pragma unroll
    for (int u = 0; u < 4; ++u) { oacc[u][0]=0.f; oacc[u][1]=0.f; oacc[u][2]=0.f; oacc[u][3]=0.f; }

    float* attn_row = attn + (bq + 16 * w + n) * 1024;
    short* pw = ptile[w];

    for (int kt = 0; kt < 16; ++kt) {
        if (kt < 15) {
            stage8k(kbuf[(kt + 1) & 1], ktg + (kt + 1) * 4096, w, L);
            stage8k(vbuf[(kt + 1) & 1], vtg + (kt + 1) * 4096, w, L);
        }
        unsigned long long mrow = mrow_ptr[kt];
        const short* kl = kbuf[kt & 1];
        const short* vl = vbuf[kt & 1];
        f32x4 acc[4];
        #pragma unroll
        for (int t = 0; t < 4; ++t) { acc[t][0]=0.f; acc[t][1]=0.f; acc[t][2]=0.f; acc[t][3]=0.f; }
        #pragma unroll
        for (int t = 0; t < 4; ++t) {
            bf16x8 kf0 = *(const bf16x8*)&kl[(t * 16 + n) * 64 + ((g ^ sw) << 3)];
            bf16x8 kf1 = *(const bf16x8*)&kl[(t * 16 + n) * 64 + (((4 + g) ^ sw) << 3)];
            acc[t] = __builtin_amdgcn_mfma_f32_16x16x32_bf16(kf0, qf0, acc[t], 0, 0, 0);
            acc[t] = __builtin_amdgcn_mfma_f32_16x16x32_bf16(kf1, qf1, acc[t], 0, 0, 0);
        }
        unsigned long long ms = mrow >> (g * 4);
        #pragma unroll
        for (int t = 0; t < 4; ++t) {
            unsigned b0 = (unsigned)(ms >> (t * 16 + 0)) & 1u;
            unsigned b1 = (unsigned)(ms >> (t * 16 + 1)) & 1u;
            unsigned b2 = (unsigned)(ms >> (t * 16 + 2)) & 1u;
            unsigned b3 = (unsigned)(ms >> (t * 16 + 3)) & 1u;
            float p0 = b0 ? 0.f : __builtin_exp2f(acc[t][0]) * linv;
            float p1 = b1 ? 0.f : __builtin_exp2f(acc[t][1]) * linv;
            float p2 = b2 ? 0.f : __builtin_exp2f(acc[t][2]) * linv;
            float p3 = b3 ? 0.f : __builtin_exp2f(acc[t][3]) * linv;
            // attn store: row = qrow(n), cols kt*64 + t*16 + g*4 .. +3 (fp32, 16B)
            *(float4*)(attn_row + kt * 64 + t * 16 + g * 4) = make_float4(p0, p1, p2, p3);
            // P^T -> LDS (A-layout source): row n, kpos t*16+g*4.. (b64, swizzled)
            *(bf16x4*)&pw[n * 64 + ((((t * 2) + (g >> 1)) ^ sw) << 3) + (g & 1) * 4] =
                pack4(p0, p1, p2, p3);
        }
        // read P as A-operand: lane holds P[qrow=n][kpos = g*8+j (+32)]
        bf16x8 pf0 = *(const bf16x8*)&pw[n * 64 + ((g ^ sw) << 3)];
        bf16x8 pf1 = *(const bf16x8*)&pw[n * 64 + (((4 + g) ^ sw) << 3)];
        // O = P @ V : B-frag = V^T rows (d = u*16+n), kpos chunks g / 4+g
        #pragma unroll
        for (int u = 0; u < 4; ++u) {
            bf16x8 vf0 = *(const bf16x8*)&vl[(u * 16 + n) * 64 + ((g ^ sw) << 3)];
            bf16x8 vf1 = *(const bf16x8*)&vl[(u * 16 + n) * 64 + (((4 + g) ^ sw) << 3)];
            oacc[u] = __builtin_amdgcn_mfma_f32_16x16x32_bf16(pf0, vf0, oacc[u], 0, 0, 0);
            oacc[u] = __builtin_amdgcn_mfma_f32_16x16x32_bf16(pf1, vf1, oacc[u], 0, 0, 0);
        }
        __syncthreads();
    }

    // O in C-layout: row g*4+i = qrow_local, col n = d within u-subtile
    #pragma unroll
    for (int u = 0; u < 4; ++u)
        #pragma unroll
        for (int i = 0; i < 4; ++i)
            out[(bq + 16 * w + g * 4 + i) * 64 + u * 16 + n] = oacc[u][i];
}

// ---------------------------------------------------------------------------
// fallback for small ws (round-1 kernel, known correct)
#define KSTRIDE 72
#define PSTRIDE 68
__global__ __launch_bounds__(256) void attn_fallback(
    const float* __restrict__ q, const float* __restrict__ k,
    const float* __restrict__ v, const int* __restrict__ mask,
    float* __restrict__ out, float* __restrict__ attn)
{
    __shared__ unsigned maskbits[64][32];
    __shared__ short kbuf[64 * KSTRIDE];
    __shared__ short vtbuf[64 * KSTRIDE];
    __shared__ float ptilef[4 * 16 * PSTRIDE];

    const int tid  = threadIdx.x;
    const int w    = tid >> 6;
    const int L    = tid & 63;
    const int n    = L & 15;
    const int quad = L >> 4;
    const int b    = blockIdx.y;
    const long bq  = (long)b * 1024 + blockIdx.x * 64;

    const float* qrow = q + (bq + 16 * w + n) * 64 + quad * 8;
    float4 qa0 = ((const float4*)qrow)[0];
    float4 qa1 = ((const float4*)(qrow + 4))[0];
    float4 qb0 = ((const float4*)(qrow + 32))[0];
    float4 qb1 = ((const float4*)(qrow + 36))[0];
    const float sc = 0.125f;
    qa0.x *= sc; qa0.y *= sc; qa0.z *= sc; qa0.w *= sc;
    qa1.x *= sc; qa1.y *= sc; qa1.z *= sc; qa1.w *= sc;
    qb0.x *= sc; qb0.y *= sc; qb0.z *= sc; qb0.w *= sc;
    qb1.x *= sc; qb1.y *= sc; qb1.z *= sc; qb1.w *= sc;
    bf16x8 qf0 = pack8(qa0, qa1);
    bf16x8 qf1 = pack8(qb0, qb1);

    #pragma unroll
    for (int ii = 0; ii < 8; ++ii) {
        int wi  = ii * 256 + tid;
        int row = wi >> 5;
        int wc  = wi & 31;
        const int4* mp = (const int4*)(mask + (bq + row) * 1024 + wc * 32);
        unsigned word = 0;
        #pragma unroll
        for (int j = 0; j < 8; ++j) {
            int4 m4 = mp[j];
            word |= (m4.x != 0 ? 1u : 0u) << (4 * j + 0);
            word |= (m4.y != 0 ? 1u : 0u) << (4 * j + 1);
            word |= (m4.z != 0 ? 1u : 0u) << (4 * j + 2);
            word |= (m4.w != 0 ? 1u : 0u) << (4 * j + 3);
        }
        maskbits[row][wc] = word;
    }

    float m_i[4] = {-1e30f, -1e30f, -1e30f, -1e30f};
    float l_i[4] = {0.f, 0.f, 0.f, 0.f};

    for (int kt = 0; kt < 16; ++kt) {
        __syncthreads();
        {
            const float* kr = k + ((long)b * 1024 + kt * 64 + L) * 64 + w * 16;
            float4 k0 = ((const float4*)kr)[0];
            float4 k1 = ((const float4*)kr)[1];
            float4 k2 = ((const float4*)kr)[2];
            float4 k3 = ((const float4*)kr)[3];
            bf16x8* dst = (bf16x8*)&kbuf[L * KSTRIDE + w * 16];
            dst[0] = pack8(k0, k1);
            dst[1] = pack8(k2, k3);
        }
        __syncthreads();
        f32x4 acc[4];
        #pragma unroll
        for (int t = 0; t < 4; ++t) { acc[t][0]=0.f; acc[t][1]=0.f; acc[t][2]=0.f; acc[t][3]=0.f; }
        #pragma unroll
        for (int t = 0; t < 4; ++t) {
            bf16x8 b0 = *(const bf16x8*)&kbuf[(t * 16 + n) * KSTRIDE + quad * 8];
            bf16x8 b1 = *(const bf16x8*)&kbuf[(t * 16 + n) * KSTRIDE + 32 + quad * 8];
            acc[t] = __builtin_amdgcn_mfma_f32_16x16x32_bf16(qf0, b0, acc[t], 0, 0, 0);
            acc[t] = __builtin_amdgcn_mfma_f32_16x16x32_bf16(qf1, b1, acc[t], 0, 0, 0);
        }
        #pragma unroll
        for (int i = 0; i < 4; ++i) {
            int mrow = 16 * w + quad * 4 + i;
            unsigned w0 = maskbits[mrow][kt * 2];
            unsigned w1 = maskbits[mrow][kt * 2 + 1];
            float s0 = ((w0 >> n)        & 1u) ? -1e30f : acc[0][i];
            float s1 = ((w0 >> (16 + n)) & 1u) ? -1e30f : acc[1][i];
            float s2 = ((w1 >> n)        & 1u) ? -1e30f : acc[2][i];
            float s3 = ((w1 >> (16 + n)) & 1u) ? -1e30f : acc[3][i];
            float mt = fmaxf(fmaxf(s0, s1), fmaxf(s2, s3));
            mt = fmaxf(mt, __shfl_xor(mt, 1));
            mt = fmaxf(mt, __shfl_xor(mt, 2));
            mt = fmaxf(mt, __shfl_xor(mt, 4));
            mt = fmaxf(mt, __shfl_xor(mt, 8));
            float mnew = fmaxf(m_i[i], mt);
            float ps = __expf(s0 - mnew) + __expf(s1 - mnew)
                     + __expf(s2 - mnew) + __expf(s3 - mnew);
            ps += __shfl_xor(ps, 1);
            ps += __shfl_xor(ps, 2);
            ps += __shfl_xor(ps, 4);
            ps += __shfl_xor(ps, 8);
            l_i[i] = l_i[i] * __expf(m_i[i] - mnew) + ps;
            m_i[i] = mnew;
        }
    }
    float linv[4];
    #pragma unroll
    for (int i = 0; i < 4; ++i) linv[i] = 1.0f / l_i[i];

    f32x4 oacc[4];
    #pragma unroll
    for (int t = 0; t < 4; ++t) { oacc[t][0]=0.f; oacc[t][1]=0.f; oacc[t][2]=0.f; oacc[t][3]=0.f; }
    float* attn_row = attn + (bq + 16 * w + n) * 1024;

    for (int kt = 0; kt < 16; ++kt) {
        __syncthreads();
        {
            const float* kr = k + ((long)b * 1024 + kt * 64 + L) * 64 + w * 16;
            float4 k0 = ((const float4*)kr)[0];
            float4 k1 = ((const float4*)kr)[1];
            float4 k2 = ((const float4*)kr)[2];
            float4 k3 = ((const float4*)kr)[3];
            bf16x8* dst = (bf16x8*)&kbuf[L * KSTRIDE + w * 16];
            dst[0] = pack8(k0, k1);
            dst[1] = pack8(k2, k3);
            const float* vr = v + ((long)b * 1024 + kt * 64 + L) * 64 + w * 16;
            float4 v0 = ((const float4*)vr)[0];
            float4 v1 = ((const float4*)vr)[1];
            float4 v2 = ((const float4*)vr)[2];
            float4 v3 = ((const float4*)vr)[3];
            float vv[16] = {v0.x, v0.y, v0.z, v0.w, v1.x, v1.y, v1.z, v1.w,
                            v2.x, v2.y, v2.z, v2.w, v3.x, v3.y, v3.z, v3.w};
            #pragma unroll
            for (int dd = 0; dd < 16; ++dd)
                vtbuf[(w * 16 + dd) * KSTRIDE + L] = f2bf(vv[dd]);
        }
        __syncthreads();
        f32x4 acc[4];
        #pragma unroll
        for (int t = 0; t < 4; ++t) { acc[t][0]=0.f; acc[t][1]=0.f; acc[t][2]=0.f; acc[t][3]=0.f; }
        #pragma unroll
        for (int t = 0; t < 4; ++t) {
            bf16x8 b0 = *(const bf16x8*)&kbuf[(t * 16 + n) * KSTRIDE + quad * 8];
            bf16x8 b1 = *(const bf16x8*)&kbuf[(t * 16 + n) * KSTRIDE + 32 + quad * 8];
            acc[t] = __builtin_amdgcn_mfma_f32_16x16x32_bf16(qf0, b0, acc[t], 0, 0, 0);
            acc[t] = __builtin_amdgcn_mfma_f32_16x16x32_bf16(qf1, b1, acc[t], 0, 0, 0);
        }
        #pragma unroll
        for (int i = 0; i < 4; ++i) {
            int mrow = 16 * w + quad * 4 + i;
            unsigned w0 = maskbits[mrow][kt * 2];
            unsigned w1 = maskbits[mrow][kt * 2 + 1];
            float s0 = ((w0 >> n)        & 1u) ? -1e30f : acc[0][i];
            float s1 = ((w0 >> (16 + n)) & 1u) ? -1e30f : acc[1][i];
            float s2 = ((w1 >> n)        & 1u) ? -1e30f : acc[2][i];
            float s3 = ((w1 >> (16 + n)) & 1u) ? -1e30f : acc[3][i];
            float* pr = &ptilef[(w * 16 + quad * 4 + i) * PSTRIDE];
            pr[n]      = __expf(s0 - m_i[i]) * linv[i];
            pr[16 + n] = __expf(s1 - m_i[i]) * linv[i];
            pr[32 + n] = __expf(s2 - m_i[i]) * linv[i];
            pr[48 + n] = __expf(s3 - m_i[i]) * linv[i];
        }
        bf16x8 pf[2];
        #pragma unroll
        for (int c = 0; c < 2; ++c) {
            const float* pp = &ptilef[(w * 16 + n) * PSTRIDE + c * 32 + quad * 8];
            float4 p0 = ((const float4*)pp)[0];
            float4 p1 = ((const float4*)pp)[1];
            float* ap = attn_row + kt * 64 + c * 32 + quad * 8;
            ((float4*)ap)[0] = p0;
            ((float4*)ap)[1] = p1;
            pf[c] = pack8(p0, p1);
        }
        #pragma unroll
        for (int t = 0; t < 4; ++t) {
            bf16x8 vb0 = *(const bf16x8*)&vtbuf[(t * 16 + n) * KSTRIDE + quad * 8];
            bf16x8 vb1 = *(const bf16x8*)&vtbuf[(t * 16 + n) * KSTRIDE + 32 + quad * 8];
            oacc[t] = __builtin_amdgcn_mfma_f32_16x16x32_bf16(pf[0], vb0, oacc[t], 0, 0, 0);
            oacc[t] = __builtin_amdgcn_mfma_f32_16x16x32_bf16(pf[1], vb1, oacc[t], 0, 0, 0);
        }
    }
    #pragma unroll
    for (int t = 0; t < 4; ++t)
        #pragma unroll
        for (int i = 0; i < 4; ++i)
            out[(bq + 16 * w + quad * 4 + i) * 64 + t * 16 + n] = oacc[t][i];
}

extern "C" void kernel_launch(void* const* d_in, const int* in_sizes, int n_in,
                              void* d_out, int out_size, void* d_ws, size_t ws_size,
                              hipStream_t stream) {
    const float* q    = (const float*)d_in[0];
    const float* k    = (const float*)d_in[1];
    const float* v    = (const float*)d_in[2];
    const int*   mask = (const int*)d_in[3];
    float* out  = (float*)d_out;
    float* attn = out + (long)64 * 1024 * 64;

    dim3 grid(16, 64, 1);
    dim3 block(256, 1, 1);

    const size_t need = (size_t)24 << 20;  // 8MB bits + 8MB K bf16 + 8MB V^T bf16
    if (ws_size >= need) {
        unsigned char* ws = (unsigned char*)d_ws;
        unsigned long long* bits = (unsigned long long*)ws;
        short* kbw = (short*)(ws + ((size_t)8 << 20));
        short* vtw = (short*)(ws + ((size_t)16 << 20));
        pre_maskpack<<<16384, 256, 0, stream>>>(mask, bits);
        pre_kv<<<3072, 256, 0, stream>>>(k, v, kbw, vtw);
        attn_main<<<grid, block, 0, stream>>>(q, bits, kbw, vtw, out, attn);
    } else {
        attn_fallback<<<grid, block, 0, stream>>>(q, k, v, mask, out, attn);
    }
}